// Round 1
// baseline (3998.827 us; speedup 1.0000x reference)
//
#include <hip/hip_runtime.h>

#define BATCH 32
#define HGRID 24
#define WGRID 24
#define DIN   768
#define HID   384
#define GATES 1536
#define SEQT  24
#define NROWS (BATCH*HGRID*WGRID)   /* 18432 feature rows */
#define NSEQ  (BATCH*HGRID)         /* 768 sequences per direction-set */
#define SCH   12                    /* sequences per recurrence block */

struct WPtrs {
  const float* Wx[4];
  const float* Wh[4];
  const float* b[4];
};

__device__ __forceinline__ float fast_sigmoid(float x) {
  x = fminf(fmaxf(x, -30.f), 30.f);
  float e = __builtin_amdgcn_exp2f(-1.44269504f * x);
  return __builtin_amdgcn_rcpf(1.0f + e);
}
__device__ __forceinline__ float fast_tanh(float x) {
  x = fminf(fmaxf(x, -15.f), 15.f);
  float e = __builtin_amdgcn_exp2f(-2.88539008f * x);   /* e^(-2x) */
  return (1.0f - e) * __builtin_amdgcn_rcpf(1.0f + e);
}

/* ---------------- Phase 1: Z[l][r][g] = X[r][:] @ Wx_l + b_l ----------------
 * M=18432, K=768, N=1536 per LSTM. Block tile 128(M)x64(N), K-tile 16,
 * 256 threads, 8x4 per-thread micro-tile. grid.x = group*24 n-tiles. */
__global__ __launch_bounds__(256) void gemm_z(const float* __restrict__ X,
                                              WPtrs P, int lbase,
                                              float* __restrict__ Z) {
  const int bx = blockIdx.x;
  const int l_local = bx / 24;
  const int n0 = (bx % 24) * 64;
  const int m0 = blockIdx.y * 128;
  const float* __restrict__ Wx   = P.Wx[lbase + l_local];
  const float* __restrict__ bias = P.b[lbase + l_local];
  float* __restrict__ Zl = Z + (size_t)l_local * NROWS * GATES;

  __shared__ float As[16][128];   /* [k][m] */
  __shared__ float Bs[16][64];    /* [k][n] */

  const int tid = threadIdx.x;
  const int tx = tid & 15;        /* n micro-tile: 4 cols  */
  const int ty = tid >> 4;        /* m micro-tile: 8 rows  */

  float acc[8][4];
#pragma unroll
  for (int i = 0; i < 8; ++i)
#pragma unroll
    for (int j = 0; j < 4; ++j) acc[i][j] = 0.f;

  const int ar = tid >> 1;          /* 0..127 row within tile */
  const int ak = (tid & 1) * 8;     /* 0 or 8 k-offset        */
  const float* Aptr = X + (size_t)(m0 + ar) * DIN + ak;
  const int bk = tid >> 4;          /* 0..15 */
  const int bc = (tid & 15) * 4;    /* 0..60 */
  const float* Bptr = Wx + (size_t)bk * GATES + n0 + bc;

  for (int k0 = 0; k0 < DIN; k0 += 16) {
    const float4 a0 = *(const float4*)(Aptr);
    const float4 a1 = *(const float4*)(Aptr + 4);
    const float4 bv = *(const float4*)(Bptr);
    Aptr += 16;
    Bptr += (size_t)16 * GATES;

    __syncthreads();   /* previous tile's compute must be done reading LDS */
    As[ak + 0][ar] = a0.x; As[ak + 1][ar] = a0.y;
    As[ak + 2][ar] = a0.z; As[ak + 3][ar] = a0.w;
    As[ak + 4][ar] = a1.x; As[ak + 5][ar] = a1.y;
    As[ak + 6][ar] = a1.z; As[ak + 7][ar] = a1.w;
    *(float4*)&Bs[bk][bc] = bv;
    __syncthreads();

#pragma unroll
    for (int k = 0; k < 16; ++k) {
      const float4 av0 = *(const float4*)&As[k][ty * 8];
      const float4 av1 = *(const float4*)&As[k][ty * 8 + 4];
      const float4 bvv = *(const float4*)&Bs[k][tx * 4];
      const float ar8[8] = {av0.x, av0.y, av0.z, av0.w,
                            av1.x, av1.y, av1.z, av1.w};
      const float br4[4] = {bvv.x, bvv.y, bvv.z, bvv.w};
#pragma unroll
      for (int i = 0; i < 8; ++i)
#pragma unroll
        for (int j = 0; j < 4; ++j)
          acc[i][j] = fmaf(ar8[i], br4[j], acc[i][j]);
    }
  }

  float bs[4];
#pragma unroll
  for (int j = 0; j < 4; ++j) bs[j] = bias[n0 + tx * 4 + j];
#pragma unroll
  for (int i = 0; i < 8; ++i) {
    const int row = m0 + ty * 8 + i;
    float4 o;
    o.x = acc[i][0] + bs[0];
    o.y = acc[i][1] + bs[1];
    o.z = acc[i][2] + bs[2];
    o.w = acc[i][3] + bs[3];
    *(float4*)&Zl[(size_t)row * GATES + n0 + tx * 4] = o;
  }
}

/* ---------------- Phase 2: recurrence --------------------------------------
 * One block = one LSTM l x 12 sequences, full T=24 recurrence.
 * 384 threads: thread q owns hidden unit q -> gate cols {q,384+q,768+q,1152+q}
 * so i/f/cand/o for (s,q) stay in-thread (no gate exchange). h in LDS [k][s]
 * (wave-uniform broadcast float4 reads); c in registers.
 * Each Wh element read exactly once per block-step. */
__global__ __launch_bounds__(384) void recur(const float* __restrict__ Z,
                                             float* __restrict__ out,
                                             WPtrs P, int lbase, int group) {
  const int bi = blockIdx.x;
  const int l_local = bi % group;       /* round-robin -> XCD L2 locality */
  const int chunk = bi / group;
  const int l = lbase + l_local;
  const float* __restrict__ Wh = P.Wh[l];
  const float* __restrict__ Zl = Z + (size_t)l_local * NROWS * GATES;
  const int q = threadIdx.x;            /* hidden unit 0..383 */
  const int n0 = chunk * SCH;
  const bool rev = (l & 1);

  __shared__ float h_lds[HID * SCH];    /* [k][s], 18 KB */

  float c[SCH];
#pragma unroll
  for (int s = 0; s < SCH; ++s) c[s] = 0.f;
#pragma unroll
  for (int s = 0; s < SCH; ++s) h_lds[q * SCH + s] = 0.f;
  __syncthreads();

  /* feature-row r(s, t): horizontal r = n*24 + t ; vertical r = (n/24)*576 + t*24 + n%24 */
  int rbase[SCH];
  int rstep;
  if (l < 2) {
    rstep = 1;
#pragma unroll
    for (int s = 0; s < SCH; ++s) rbase[s] = (n0 + s) * SEQT;
  } else {
    rstep = 24;
#pragma unroll
    for (int s = 0; s < SCH; ++s) {
      const int n = n0 + s;
      rbase[s] = (n / 24) * 576 + (n % 24);
    }
  }

  for (int it = 0; it < SEQT; ++it) {
    const int tt = rev ? (SEQT - 1 - it) : it;

    float gi[SCH], gf[SCH], gc[SCH], go[SCH];
#pragma unroll
    for (int s = 0; s < SCH; ++s) {
      const float* zrow = Zl + (size_t)(rbase[s] + tt * rstep) * GATES;
      gi[s] = zrow[q];
      gf[s] = zrow[384 + q];
      gc[s] = zrow[768 + q];
      go[s] = zrow[1152 + q];
    }

    const float* whp = Wh + q;
#pragma unroll 2
    for (int k = 0; k < HID; ++k) {
      const float wi = whp[0];
      const float wf = whp[384];
      const float wc = whp[768];
      const float wo = whp[1152];
      whp += GATES;
      const float4 h0 = *(const float4*)&h_lds[k * SCH];
      const float4 h1 = *(const float4*)&h_lds[k * SCH + 4];
      const float4 h2 = *(const float4*)&h_lds[k * SCH + 8];
      const float hv[SCH] = {h0.x, h0.y, h0.z, h0.w,
                             h1.x, h1.y, h1.z, h1.w,
                             h2.x, h2.y, h2.z, h2.w};
#pragma unroll
      for (int s = 0; s < SCH; ++s) {
        gi[s] = fmaf(hv[s], wi, gi[s]);
        gf[s] = fmaf(hv[s], wf, gf[s]);
        gc[s] = fmaf(hv[s], wc, gc[s]);
        go[s] = fmaf(hv[s], wo, go[s]);
      }
    }

    __syncthreads();   /* all GEMM reads of old h done before overwrite */
#pragma unroll
    for (int s = 0; s < SCH; ++s) {
      const float ig = fast_sigmoid(gi[s]);
      const float fg = fast_sigmoid(gf[s]);
      const float cd = fast_tanh(gc[s]);
      const float og = fast_sigmoid(go[s]);
      const float cn = fmaf(fg, c[s], ig * cd);
      c[s] = cn;
      const float hn = og * fast_tanh(cn);
      h_lds[q * SCH + s] = hn;
      out[(size_t)(rbase[s] + tt * rstep) * GATES + l * HID + q] = hn;
    }
    __syncthreads();
  }
}

extern "C" void kernel_launch(void* const* d_in, const int* in_sizes, int n_in,
                              void* d_out, int out_size, void* d_ws, size_t ws_size,
                              hipStream_t stream) {
  const float* feat = (const float*)d_in[0];
  WPtrs P;
  P.Wx[0] = (const float*)d_in[1];  P.Wh[0] = (const float*)d_in[2];  P.b[0] = (const float*)d_in[3];
  P.Wx[1] = (const float*)d_in[4];  P.Wh[1] = (const float*)d_in[5];  P.b[1] = (const float*)d_in[6];
  P.Wx[2] = (const float*)d_in[7];  P.Wh[2] = (const float*)d_in[8];  P.b[2] = (const float*)d_in[9];
  P.Wx[3] = (const float*)d_in[10]; P.Wh[3] = (const float*)d_in[11]; P.b[3] = (const float*)d_in[12];
  float* out = (float*)d_out;
  float* Z = (float*)d_ws;

  const size_t slabB = (size_t)NROWS * GATES * sizeof(float);  /* 113.25 MB per LSTM */
  const int group = (ws_size >= 4 * slabB) ? 4 : (ws_size >= 2 * slabB) ? 2 : 1;

  for (int lbase = 0; lbase < 4; lbase += group) {
    gemm_z<<<dim3(24 * group, NROWS / 128), 256, 0, stream>>>(feat, P, lbase, Z);
    recur<<<dim3((NSEQ / SCH) * group), 384, 0, stream>>>(Z, out, P, lbase, group);
  }
}